// Round 14
// baseline (299.166 us; speedup 1.0000x reference)
//
#include <hip/hip_runtime.h>
#include <hip/hip_bf16.h>
#include <stdint.h>

// ---------------------------------------------------------------------------
// TinyLlamaGQA: B=4 S=2048 H=768 NH=12 NKV=4 D=64
// outputs: out0 (B,S,768) fp32  then attn (B,12,S,S) fp32, concatenated flat.
// ---------------------------------------------------------------------------

typedef __bf16 bf16x8 __attribute__((ext_vector_type(8)));
typedef float  f32x4  __attribute__((ext_vector_type(4)));

#define B_    4
#define S_    2048
#define H_    768
#define NH_Q  12
#define NKV_  4
#define D_    64
#define MROWS (B_ * S_)   // 8192
#define NQKV  1280        // 768 + 256 + 256
#define TILE_E (128 * 32) // LDS tile elements per buffer

__device__ __forceinline__ f32x4 mfma16(bf16x8 a, bf16x8 b, f32x4 c) {
  return __builtin_amdgcn_mfma_f32_16x16x32_bf16(a, b, c, 0, 0, 0);
}

__device__ __forceinline__ void st_nt4(float* p, f32x4 v) {
  __builtin_nontemporal_store(v, (f32x4*)p);
}

__device__ __forceinline__ uint32_t pk2(float a, float b) {
  __bf16 x = (__bf16)a, y = (__bf16)b;
  uint16_t xu = __builtin_bit_cast(uint16_t, x);
  uint16_t yu = __builtin_bit_cast(uint16_t, y);
  return (uint32_t)xu | ((uint32_t)yu << 16);
}
__device__ __forceinline__ float bl(uint32_t u) {
  uint32_t t = u << 16; return __builtin_bit_cast(float, t);
}
__device__ __forceinline__ float bh(uint32_t u) {
  uint32_t t = u & 0xffff0000u; return __builtin_bit_cast(float, t);
}

// async global->LDS, 16B/lane; LDS dest is wave-uniform base + lane*16.
__device__ __forceinline__ void gload_lds16(const __bf16* g, __bf16* l) {
  __builtin_amdgcn_global_load_lds(
      (const __attribute__((address_space(1))) void*)g,
      (__attribute__((address_space(3))) void*)l, 16, 0, 0);
}

// ----------------- fused cast fp32 -> bf16 (all 5 tensors) -----------------
__global__ void cast_all(const float* __restrict__ X, const float* __restrict__ wq,
                         const float* __restrict__ wo, const float* __restrict__ wk,
                         const float* __restrict__ wv,
                         __bf16* __restrict__ Xb, __bf16* __restrict__ wqb,
                         __bf16* __restrict__ wob, __bf16* __restrict__ wkb,
                         __bf16* __restrict__ wvb) {
  int i = blockIdx.x * 256 + threadIdx.x;  // 8-element item
  const int nX = MROWS * 768 / 8;   // 786432
  const int nW = 768 * 768 / 8;     // 73728
  const int nK = 256 * 768 / 8;     // 24576
  const float* s; __bf16* d; int off;
  if (i < nX)                    { s = X;  d = Xb;  off = i; }
  else if (i < nX + nW)          { s = wq; d = wqb; off = i - nX; }
  else if (i < nX + 2 * nW)      { s = wo; d = wob; off = i - nX - nW; }
  else if (i < nX + 2 * nW + nK) { s = wk; d = wkb; off = i - nX - 2 * nW; }
  else if (i < nX + 2 * nW + 2 * nK) { s = wv; d = wvb; off = i - nX - 2 * nW - nK; }
  else return;
  const float4* sp = (const float4*)s + (size_t)off * 2;
  float4 a = sp[0], b = sp[1];
  bf16x8 o;
  o[0] = (__bf16)a.x; o[1] = (__bf16)a.y; o[2] = (__bf16)a.z; o[3] = (__bf16)a.w;
  o[4] = (__bf16)b.x; o[5] = (__bf16)b.y; o[6] = (__bf16)b.z; o[7] = (__bf16)b.w;
  *((bf16x8*)d + off) = o;
}

// ------------------------- GEMM core (2-phase dbuf) ------------------------
// 128x128 tile, BK=32, 256 threads / 4 waves. Double-buffered LDS staged via
// global_load_lds with PRE-SWIZZLED global source (linear LDS dest); swizzled
// ds_read (slot = grp ^ ((row>>1)&3)) is bank-conflict-free. Stage(next)
// BEFORE compute(cur); one barrier per K-step.
struct GemmPtrs {
  const __bf16 *gA0, *gA1, *gB0, *gB1;
};

__device__ __forceinline__ GemmPtrs make_ptrs(const __bf16* A, const __bf16* W,
                                              int m0, int n0, int K, int tid) {
  GemmPtrs gp;
  int c0 = tid, c1 = 256 + tid;
  int sr0 = c0 >> 2, kc0 = (c0 & 3) ^ ((sr0 >> 1) & 3);
  int sr1 = c1 >> 2, kc1 = (c1 & 3) ^ ((sr1 >> 1) & 3);
  gp.gA0 = A + (size_t)(m0 + sr0) * K + kc0 * 8;
  gp.gA1 = A + (size_t)(m0 + sr1) * K + kc1 * 8;
  gp.gB0 = W + (size_t)(n0 + sr0) * K + kc0 * 8;
  gp.gB1 = W + (size_t)(n0 + sr1) * K + kc1 * 8;
  return gp;
}

__device__ __forceinline__ void gemm_stage(GemmPtrs gp, int k0,
                                           __bf16* As, __bf16* Bs, int tid) {
  __bf16* lA0 = As + (size_t)(tid & ~63) * 8;
  __bf16* lB0 = Bs + (size_t)(tid & ~63) * 8;
  gload_lds16(gp.gA0 + k0, lA0);
  gload_lds16(gp.gA1 + k0, lA0 + 256 * 8);
  gload_lds16(gp.gB0 + k0, lB0);
  gload_lds16(gp.gB1 + k0, lB0 + 256 * 8);
}

__device__ __forceinline__ void gemm_core(GemmPtrs gp, int K,
                                          __bf16* As, __bf16* Bs,
                                          int tid, f32x4 (*acc)[4]) {
  const int lane = tid & 63, w = tid >> 6;
  const int wm = w >> 1, wn = w & 1;
  const int ql = lane & 15, grp = lane >> 4;

  gemm_stage(gp, 0, As, Bs, tid);
  __syncthreads();  // drains the prologue stage

  const int nk = K / 32;
  for (int ks = 0; ks < nk; ks++) {
    __bf16* curA = As + (ks & 1) * TILE_E;
    __bf16* curB = Bs + (ks & 1) * TILE_E;
    if (ks + 1 < nk)  // issue next-tile loads BEFORE compute; they fly under it
      gemm_stage(gp, (ks + 1) * 32, As + ((ks + 1) & 1) * TILE_E,
                 Bs + ((ks + 1) & 1) * TILE_E, tid);

    bf16x8 af[4], bf_[4];
#pragma unroll
    for (int i = 0; i < 4; i++) {
      int row = wm * 64 + i * 16 + ql;
      int kc = grp ^ ((row >> 1) & 3);
      af[i] = *(const bf16x8*)(curA + row * 32 + kc * 8);
    }
#pragma unroll
    for (int j = 0; j < 4; j++) {
      int row = wn * 64 + j * 16 + ql;
      int kc = grp ^ ((row >> 1) & 3);
      bf_[j] = *(const bf16x8*)(curB + row * 32 + kc * 8);
    }
#pragma unroll
    for (int i = 0; i < 4; i++)
#pragma unroll
      for (int j = 0; j < 4; j++)
        acc[i][j] = mfma16(af[i], bf_[j], acc[i][j]);
    __syncthreads();  // waits vmcnt(0): next buffer staged; cur reads done
  }
}

__device__ __forceinline__ void gemm_store(f32x4 (*acc)[4], float* C, int N,
                                           int m0, int n0, int tid) {
  const int lane = tid & 63, w = tid >> 6;
  const int wm = w >> 1, wn = w & 1;
  const int ql = lane & 15, grp = lane >> 4;
#pragma unroll
  for (int i = 0; i < 4; i++)
#pragma unroll
    for (int j = 0; j < 4; j++)
#pragma unroll
      for (int r = 0; r < 4; r++) {
        int row = m0 + wm * 64 + i * 16 + grp * 4 + r;
        int col = n0 + wn * 64 + j * 16 + ql;
        C[(size_t)row * N + col] = acc[i][j][r];
      }
}

// ------ fused QKV GEMM + RoPE epilogue -------------------------------------
// Q/K tiles: RoPE applied in-register (pair partner = shfl_xor(acc,1), since
// pair columns are adjacent and col parity == ql parity), store bf16 directly
// in attention layout (B,NH,S,64). Q pre-scaled by (1/8)*log2(e).
// V tiles: store bf16 rows to Vrow (8192 x 256) for the transpose kernel.
__global__ __launch_bounds__(256) void gemm_qkv(const __bf16* __restrict__ A,
                                                const __bf16* __restrict__ Wq,
                                                const __bf16* __restrict__ Wk,
                                                const __bf16* __restrict__ Wv,
                                                const float* __restrict__ fc,
                                                const float* __restrict__ fs,
                                                __bf16* __restrict__ Qb,
                                                __bf16* __restrict__ Kb,
                                                __bf16* __restrict__ Vrow) {
  __shared__ __bf16 As[2 * TILE_E];
  __shared__ __bf16 Bs[2 * TILE_E];
  const int m0 = blockIdx.x * 128, n0 = blockIdx.y * 128;
  const __bf16* W;
  int nl;
  if (n0 < 768)       { W = Wq; nl = n0; }
  else if (n0 < 1024) { W = Wk; nl = n0 - 768; }
  else                { W = Wv; nl = n0 - 1024; }
  const int tid = threadIdx.x;
  f32x4 acc[4][4] = {};
  GemmPtrs gp = make_ptrs(A, W, m0, nl, 768, tid);
  gemm_core(gp, 768, As, Bs, tid, acc);

  const int lane = tid & 63, w = tid >> 6;
  const int wm = w >> 1, wn = w & 1;
  const int ql = lane & 15, grp = lane >> 4;

  if (n0 < 1024) {
    // ---- RoPE epilogue (Q or K) ----
    __bf16* dst; int NH, hbase; float scale;
    if (n0 < 768) { dst = Qb; NH = NH_Q; hbase = 0;   scale = 0.125f * 1.44269504f; }
    else          { dst = Kb; NH = NKV_; hbase = 768; scale = 1.0f; }
#pragma unroll
    for (int i = 0; i < 4; i++)
#pragma unroll
      for (int j = 0; j < 4; j++) {
        const int col = n0 + wn * 64 + j * 16 + ql;
        const int hd = col - hbase;
        const int h = hd >> 6, d = hd & 63, t = d >> 1;
        const bool ev = (d & 1) == 0;
#pragma unroll
        for (int r = 0; r < 4; r++) {
          const int row = m0 + wm * 64 + i * 16 + grp * 4 + r;
          const int s = row & (S_ - 1), b = row >> 11;
          float x = acc[i][j][r];
          float xo = __shfl_xor(x, 1);  // pair partner (col^1)
          float c = fc[s * 32 + t], sn = fs[s * 32 + t];
          float o = ev ? (x * c - xo * sn) : (xo * sn + x * c);
          dst[(((size_t)(b * NH + h) * S_ + s) << 6) + d] = (__bf16)(o * scale);
        }
      }
  } else {
    // ---- V epilogue: bf16 rows (8192 x 256) ----
#pragma unroll
    for (int i = 0; i < 4; i++)
#pragma unroll
      for (int j = 0; j < 4; j++) {
        const int colv = n0 - 1024 + wn * 64 + j * 16 + ql;
#pragma unroll
        for (int r = 0; r < 4; r++) {
          const int row = m0 + wm * 64 + i * 16 + grp * 4 + r;
          Vrow[(size_t)row * 256 + colv] = (__bf16)acc[i][j][r];
        }
      }
  }
}

// ------------------------- GEMM: C = A(bf16) * W^T -------------------------
__global__ __launch_bounds__(256) void gemm_xwT(const __bf16* __restrict__ A,
                                                const __bf16* __restrict__ W,
                                                float* __restrict__ C,
                                                int M, int N, int K) {
  __shared__ __bf16 As[2 * TILE_E];
  __shared__ __bf16 Bs[2 * TILE_E];
  const int m0 = blockIdx.x * 128, n0 = blockIdx.y * 128;
  const int tid = threadIdx.x;
  f32x4 acc[4][4] = {};
  GemmPtrs gp = make_ptrs(A, W, m0, n0, K, tid);
  gemm_core(gp, K, As, Bs, tid, acc);
  gemm_store(acc, C, N, m0, n0, tid);
}

// --------- V: (8192,256) bf16 rows -> VT (B,4,64,2048) bf16 ----------------
__global__ void transpose_v(const __bf16* __restrict__ Vrow, __bf16* __restrict__ VT) {
  __shared__ float tile[64][65];
  int rt = blockIdx.x;  // 0..127
  int ct = blockIdx.y;  // 0..3
  int r0 = rt * 64, c0 = ct * 64;
  int tx = threadIdx.x & 63, ty = threadIdx.x >> 6;
#pragma unroll
  for (int rep = 0; rep < 16; rep++) {
    int rr = rep * 4 + ty;
    tile[rr][tx] = (float)Vrow[(size_t)(r0 + rr) * 256 + c0 + tx];
  }
  __syncthreads();
  int b = r0 >> 11;
  int s0 = r0 & (S_ - 1);
#pragma unroll
  for (int rep = 0; rep < 16; rep++) {
    int dr = rep * 4 + ty;
    int d = c0 + dr;
    int kv = d >> 6, dd = d & 63;
    VT[(((size_t)(b * NKV_ + kv) * 64 + dd) * S_) + s0 + tx] = (__bf16)tile[tx][dr];
  }
}

// ------------------------------- attention ---------------------------------
// R7 structure (best measured): single-pass, P in registers (packed bf16);
// phase 1 = QK^T+exp2; barrier; phase 2 = V loads + shfl + PV MFMA + attn
// stores. XCD-grouped 1-D grid keeps each (h,b)'s K/V L2-resident.
template <int MAXC>
__device__ __forceinline__ void attn_part(
    int g, int b, int h, int w, int lane,
    const __bf16* __restrict__ Q, const __bf16* __restrict__ Kp,
    const __bf16* __restrict__ Vp, float* __restrict__ attn,
    __bf16* __restrict__ O, float (*lsum_s)[16], f32x4 (*obuf)[4]) {
  const int ql = lane & 15, grp = lane >> 4;
  const int qr0 = g * 16;
  const int nch = (g >> 1) + 1;
  const int i_q = qr0 + ql;
  const __bf16* Qp = Q + ((size_t)(b * NH_Q + h) * S_ + qr0) * 64;
  float* attnp = attn + ((size_t)(b * NH_Q + h) * S_ + qr0) * S_;

  bf16x8 bq0 = *(const bf16x8*)(Qp + ql * 64 + grp * 8);
  bf16x8 bq1 = *(const bf16x8*)(Qp + ql * 64 + 32 + grp * 8);

  uint32_t p[MAXC][4];
  float lsum = 0.f;

  // ---- phase 1: QK^T + exp2, P -> registers (packed bf16) ----
#pragma unroll
  for (int c = 0; c < MAXC; c++) {
    const int j = w + 4 * c;
    if (j < nch) {
      const int j0 = j * 32;
      bf16x8 k0 = *(const bf16x8*)(Kp + (size_t)(j0 + ql) * 64 + grp * 8);
      bf16x8 k1 = *(const bf16x8*)(Kp + (size_t)(j0 + ql) * 64 + 32 + grp * 8);
      bf16x8 k2 = *(const bf16x8*)(Kp + (size_t)(j0 + 16 + ql) * 64 + grp * 8);
      bf16x8 k3 = *(const bf16x8*)(Kp + (size_t)(j0 + 16 + ql) * 64 + 32 + grp * 8);
      f32x4 s0 = {}, s1 = {};
      s0 = mfma16(k0, bq0, s0);
      s0 = mfma16(k1, bq1, s0);
      s1 = mfma16(k2, bq0, s1);
      s1 = mfma16(k3, bq1, s1);
      float e[8];
      if (j == nch - 1) {  // only the last chunk is causally masked
#pragma unroll
        for (int r = 0; r < 4; r++) {
          int ja = j0 + grp * 4 + r, jb = j0 + 16 + grp * 4 + r;
          e[r]     = (ja <= i_q) ? exp2f(s0[r]) : 0.f;
          e[4 + r] = (jb <= i_q) ? exp2f(s1[r]) : 0.f;
        }
      } else {
#pragma unroll
        for (int r = 0; r < 4; r++) {
          e[r]     = exp2f(s0[r]);
          e[4 + r] = exp2f(s1[r]);
        }
      }
#pragma unroll
      for (int r = 0; r < 8; r++) lsum += e[r];
      p[c][0] = pk2(e[0], e[1]);
      p[c][1] = pk2(e[2], e[3]);
      p[c][2] = pk2(e[4], e[5]);
      p[c][3] = pk2(e[6], e[7]);
    }
  }

  // ---- cross-lane + cross-wave row-sum ----
  lsum += __shfl_xor(lsum, 16);
  lsum += __shfl_xor(lsum, 32);
  if (lane < 16) lsum_s[w][ql] = lsum;
  __syncthreads();
  const float rinv = 1.f / (lsum_s[0][ql] + lsum_s[1][ql] + lsum_s[2][ql] + lsum_s[3][ql]);

  // ---- phase 2: normalize+write attn, PV MFMA ----
  f32x4 opv[4] = {};
#pragma unroll
  for (int c = 0; c < MAXC; c++) {
    const int j = w + 4 * c;
    if (j < nch) {
      const int j0 = j * 32;
      bf16x8 v0 = *(const bf16x8*)(Vp + (size_t)(0 * 16 + ql) * S_ + j0 + grp * 8);
      bf16x8 v1 = *(const bf16x8*)(Vp + (size_t)(1 * 16 + ql) * S_ + j0 + grp * 8);
      bf16x8 v2 = *(const bf16x8*)(Vp + (size_t)(2 * 16 + ql) * S_ + j0 + grp * 8);
      bf16x8 v3 = *(const bf16x8*)(Vp + (size_t)(3 * 16 + ql) * S_ + j0 + grp * 8);

      f32x4 q0, q1;
      q0[0] = bl(p[c][0]); q0[1] = bh(p[c][0]); q0[2] = bl(p[c][1]); q0[3] = bh(p[c][1]);
      q1[0] = bl(p[c][2]); q1[1] = bh(p[c][2]); q1[2] = bl(p[c][3]); q1[3] = bh(p[c][3]);
#pragma unroll
      for (int r = 0; r < 4; r++) { q0[r] *= rinv; q1[r] *= rinv; }
      st_nt4(attnp + (size_t)ql * S_ + j0 + grp * 4, q0);
      st_nt4(attnp + (size_t)ql * S_ + j0 + 16 + grp * 4, q1);

      int srcA = ql + 32 * (grp & 1);
      int srcB = srcA + 16;
      uint32_t A0 = __shfl(p[c][0], srcA), A1 = __shfl(p[c][1], srcA);
      uint32_t A2 = __shfl(p[c][2], srcA), A3 = __shfl(p[c][3], srcA);
      uint32_t B0 = __shfl(p[c][0], srcB), B1 = __shfl(p[c][1], srcB);
      uint32_t B2 = __shfl(p[c][2], srcB), B3 = __shfl(p[c][3], srcB);
      bool hi = (grp >> 1) != 0;
      union { bf16x8 v; uint32_t u[4]; } pu;
      pu.u[0] = hi ? A2 : A0;
      pu.u[1] = hi ? A3 : A1;
      pu.u[2] = hi ? B2 : B0;
      pu.u[3] = hi ? B3 : B1;
      opv[0] = mfma16(pu.v, v0, opv[0]);
      opv[1] = mfma16(pu.v, v1, opv[1]);
      opv[2] = mfma16(pu.v, v2, opv[2]);
      opv[3] = mfma16(pu.v, v3, opv[3]);
    }
  }

  // ---- cross-wave O reduce + write (unnormalized opv; scale by row rinv) ----
  f32x4* ob = obuf[w * 64 + lane];
  ob[0] = opv[0]; ob[1] = opv[1]; ob[2] = opv[2]; ob[3] = opv[3];
  __syncthreads();
  {
    const int dt = w;
    f32x4 acc = obuf[0 * 64 + lane][dt];
    acc += obuf[1 * 64 + lane][dt];
    acc += obuf[2 * 64 + lane][dt];
    acc += obuf[3 * 64 + lane][dt];
    __bf16* Op = O + ((size_t)(b * S_) + qr0) * H_ + h * 64;
#pragma unroll
    for (int r = 0; r < 4; r++) {
      int row = grp * 4 + r;
      float rr = 1.f / (lsum_s[0][row] + lsum_s[1][row] + lsum_s[2][row] + lsum_s[3][row]);
      Op[(size_t)row * H_ + dt * 16 + ql] = (__bf16)(acc[r] * rr);
    }
  }

  // ---- zero causal tail [nch*32, S) cooperatively (256 threads) ----
  const int jz = nch * 32;
  const int tid = w * 64 + lane;
  const f32x4 z4 = {0.f, 0.f, 0.f, 0.f};
#pragma unroll 1
  for (int rr = 0; rr < 16; rr++) {
    float* rowp = attnp + (size_t)rr * S_;
    for (int jj = jz + tid * 4; jj < S_; jj += 1024) st_nt4(rowp + jj, z4);
  }
  __syncthreads();  // protect lsum_s/obuf for the next part
}

__global__ __launch_bounds__(256) void attn_kernel(const __bf16* __restrict__ Q,
                                                   const __bf16* __restrict__ Kb,
                                                   const __bf16* __restrict__ VT,
                                                   float* __restrict__ attn,
                                                   __bf16* __restrict__ O) {
  __shared__ float lsum_s[4][16];
  __shared__ f32x4 obuf[4 * 64][4];
  // XCD-grouping decode (bijective): bid = r + 8*(x + 64*idx6),
  // g48 = idx6*8 + r -> (h,b); all blocks of one (h,b) share bid%8 -> one XCD.
  const int bid = blockIdx.x;
  const int r = bid & 7;
  const int qd = bid >> 3;
  const int x = qd & 63;
  const int idx6 = qd >> 6;        // 0..5
  const int g48 = idx6 * 8 + r;    // 0..47
  const int h = g48 >> 2, b = g48 & 3;
  const int lane = threadIdx.x & 63, w = threadIdx.x >> 6;
  const int kv = h / 3;
  const __bf16* Kp = Kb + (size_t)(b * NKV_ + kv) * S_ * 64;
  const __bf16* Vp = VT + (size_t)(b * NKV_ + kv) * 64 * S_;

  attn_part<8>(x, b, h, w, lane, Q, Kp, Vp, attn, O, lsum_s, obuf);        // g = 0..63
  attn_part<16>(127 - x, b, h, w, lane, Q, Kp, Vp, attn, O, lsum_s, obuf); // g = 64..127
}

// ---------------------------------------------------------------------------
extern "C" void kernel_launch(void* const* d_in, const int* in_sizes, int n_in,
                              void* d_out, int out_size, void* d_ws, size_t ws_size,
                              hipStream_t stream) {
  (void)in_sizes; (void)n_in;
  const float* X  = (const float*)d_in[0];
  const float* fc = (const float*)d_in[1];
  const float* fs = (const float*)d_in[2];
  const float* wq = (const float*)d_in[3];
  const float* wk = (const float*)d_in[4];
  const float* wv = (const float*)d_in[5];
  const float* wo = (const float*)d_in[6];
  float* out0 = (float*)d_out;
  float* attn = out0 + (size_t)B_ * S_ * H_;

  // ---- scratch layout ----
  char* p = (char*)d_ws;
  auto take = [&](size_t bytes) -> char* {
    char* r = p;
    p += (bytes + 255) & ~(size_t)255;
    return r;
  };
  __bf16* wqbf = (__bf16*)take((size_t)768 * 768 * 2);
  __bf16* wkbf = (__bf16*)take((size_t)256 * 768 * 2);
  __bf16* wvbf = (__bf16*)take((size_t)256 * 768 * 2);
  __bf16* wobf = (__bf16*)take((size_t)768 * 768 * 2);
  __bf16* Qbf  = (__bf16*)take((size_t)MROWS * 768 * 2);
  __bf16* Kbf  = (__bf16*)take((size_t)MROWS * 256 * 2);
  __bf16* VTbf = (__bf16*)take((size_t)MROWS * 256 * 2);
  __bf16* Obf  = (__bf16*)take((size_t)MROWS * 768 * 2);
  size_t used = (size_t)(p - (char*)d_ws);

  const size_t XBF_B  = (size_t)MROWS * 768 * 2;
  const size_t VROW_B = (size_t)MROWS * 256 * 2;
  const size_t TEMP_B = XBF_B + VROW_B;

  char* tp;
  if (used + TEMP_B + 1024 <= ws_size) {
    tp = p;
  } else {
    // tail of the attn output region; fully consumed before attn_kernel writes
    tp = (char*)(((uintptr_t)((char*)d_out + (size_t)out_size * 4 - TEMP_B)) & ~(uintptr_t)255);
  }
  __bf16* Xbf  = (__bf16*)tp;  tp += XBF_B;
  __bf16* Vrow = (__bf16*)tp;

  // ---- 1. fused casts (one launch) ----
  {
    const int total8 = MROWS * 768 / 8 + 2 * (768 * 768 / 8) + 2 * (256 * 768 / 8);
    cast_all<<<(total8 + 255) / 256, 256, 0, stream>>>(X, wq, wo, wk, wv,
                                                       Xbf, wqbf, wobf, wkbf, wvbf);
  }

  // ---- 2. fused QKV projection + RoPE epilogue (writes Qbf/Kbf/Vrow) ----
  gemm_qkv<<<dim3(MROWS / 128, NQKV / 128), 256, 0, stream>>>(
      Xbf, wqbf, wkbf, wvbf, fc, fs, Qbf, Kbf, Vrow);

  // ---- 3. V transpose (bf16 in, bf16 out) ----
  transpose_v<<<dim3(MROWS / 64, 4), 256, 0, stream>>>(Vrow, VTbf);

  // ---- 4. attention (writes attn fp32 + Obf bf16) ----
  attn_kernel<<<dim3(48 * 64), 256, 0, stream>>>(Qbf, Kbf, VTbf, attn, Obf);

  // ---- 5. output projection ----
  gemm_xwT<<<dim3(MROWS / 128, 768 / 128), 256, 0, stream>>>(Obf, wobf, out0, MROWS, 768, 768);
}

// Round 15
// 287.068 us; speedup vs baseline: 1.0421x; 1.0421x over previous
//
#include <hip/hip_runtime.h>
#include <hip/hip_bf16.h>
#include <stdint.h>

// ---------------------------------------------------------------------------
// TinyLlamaGQA: B=4 S=2048 H=768 NH=12 NKV=4 D=64
// outputs: out0 (B,S,768) fp32  then attn (B,12,S,S) fp32, concatenated flat.
// ---------------------------------------------------------------------------

typedef __bf16 bf16x8 __attribute__((ext_vector_type(8)));
typedef float  f32x4  __attribute__((ext_vector_type(4)));

#define B_    4
#define S_    2048
#define H_    768
#define NH_Q  12
#define NKV_  4
#define D_    64
#define MROWS (B_ * S_)   // 8192
#define NQKV  1280        // 768 + 256 + 256
#define TILE_E (128 * 32) // LDS tile elements per buffer

__device__ __forceinline__ f32x4 mfma16(bf16x8 a, bf16x8 b, f32x4 c) {
  return __builtin_amdgcn_mfma_f32_16x16x32_bf16(a, b, c, 0, 0, 0);
}

__device__ __forceinline__ void st_nt4(float* p, f32x4 v) {
  __builtin_nontemporal_store(v, (f32x4*)p);
}

__device__ __forceinline__ uint32_t pk2(float a, float b) {
  __bf16 x = (__bf16)a, y = (__bf16)b;
  uint16_t xu = __builtin_bit_cast(uint16_t, x);
  uint16_t yu = __builtin_bit_cast(uint16_t, y);
  return (uint32_t)xu | ((uint32_t)yu << 16);
}
__device__ __forceinline__ float bl(uint32_t u) {
  uint32_t t = u << 16; return __builtin_bit_cast(float, t);
}
__device__ __forceinline__ float bh(uint32_t u) {
  uint32_t t = u & 0xffff0000u; return __builtin_bit_cast(float, t);
}

// async global->LDS, 16B/lane; LDS dest is wave-uniform base + lane*16.
__device__ __forceinline__ void gload_lds16(const __bf16* g, __bf16* l) {
  __builtin_amdgcn_global_load_lds(
      (const __attribute__((address_space(1))) void*)g,
      (__attribute__((address_space(3))) void*)l, 16, 0, 0);
}

// ----------------- fused cast fp32 -> bf16 (all 5 tensors) -----------------
__global__ void cast_all(const float* __restrict__ X, const float* __restrict__ wq,
                         const float* __restrict__ wo, const float* __restrict__ wk,
                         const float* __restrict__ wv,
                         __bf16* __restrict__ Xb, __bf16* __restrict__ wqb,
                         __bf16* __restrict__ wob, __bf16* __restrict__ wkb,
                         __bf16* __restrict__ wvb) {
  int i = blockIdx.x * 256 + threadIdx.x;  // 8-element item
  const int nX = MROWS * 768 / 8;   // 786432
  const int nW = 768 * 768 / 8;     // 73728
  const int nK = 256 * 768 / 8;     // 24576
  const float* s; __bf16* d; int off;
  if (i < nX)                    { s = X;  d = Xb;  off = i; }
  else if (i < nX + nW)          { s = wq; d = wqb; off = i - nX; }
  else if (i < nX + 2 * nW)      { s = wo; d = wob; off = i - nX - nW; }
  else if (i < nX + 2 * nW + nK) { s = wk; d = wkb; off = i - nX - 2 * nW; }
  else if (i < nX + 2 * nW + 2 * nK) { s = wv; d = wvb; off = i - nX - 2 * nW - nK; }
  else return;
  const float4* sp = (const float4*)s + (size_t)off * 2;
  float4 a = sp[0], b = sp[1];
  bf16x8 o;
  o[0] = (__bf16)a.x; o[1] = (__bf16)a.y; o[2] = (__bf16)a.z; o[3] = (__bf16)a.w;
  o[4] = (__bf16)b.x; o[5] = (__bf16)b.y; o[6] = (__bf16)b.z; o[7] = (__bf16)b.w;
  *((bf16x8*)d + off) = o;
}

// ------------------------- GEMM core (2-phase dbuf) ------------------------
// 128x128 tile, BK=32, 256 threads / 4 waves. Double-buffered LDS staged via
// global_load_lds with PRE-SWIZZLED global source (linear LDS dest); swizzled
// ds_read (slot = grp ^ ((row>>1)&3)) is bank-conflict-free. Stage(next)
// BEFORE compute(cur); one barrier per K-step.
struct GemmPtrs {
  const __bf16 *gA0, *gA1, *gB0, *gB1;
};

__device__ __forceinline__ GemmPtrs make_ptrs(const __bf16* A, const __bf16* W,
                                              int m0, int n0, int K, int tid) {
  GemmPtrs gp;
  int c0 = tid, c1 = 256 + tid;
  int sr0 = c0 >> 2, kc0 = (c0 & 3) ^ ((sr0 >> 1) & 3);
  int sr1 = c1 >> 2, kc1 = (c1 & 3) ^ ((sr1 >> 1) & 3);
  gp.gA0 = A + (size_t)(m0 + sr0) * K + kc0 * 8;
  gp.gA1 = A + (size_t)(m0 + sr1) * K + kc1 * 8;
  gp.gB0 = W + (size_t)(n0 + sr0) * K + kc0 * 8;
  gp.gB1 = W + (size_t)(n0 + sr1) * K + kc1 * 8;
  return gp;
}

__device__ __forceinline__ void gemm_stage(GemmPtrs gp, int k0,
                                           __bf16* As, __bf16* Bs, int tid) {
  __bf16* lA0 = As + (size_t)(tid & ~63) * 8;
  __bf16* lB0 = Bs + (size_t)(tid & ~63) * 8;
  gload_lds16(gp.gA0 + k0, lA0);
  gload_lds16(gp.gA1 + k0, lA0 + 256 * 8);
  gload_lds16(gp.gB0 + k0, lB0);
  gload_lds16(gp.gB1 + k0, lB0 + 256 * 8);
}

__device__ __forceinline__ void gemm_core(GemmPtrs gp, int K,
                                          __bf16* As, __bf16* Bs,
                                          int tid, f32x4 (*acc)[4]) {
  const int lane = tid & 63, w = tid >> 6;
  const int wm = w >> 1, wn = w & 1;
  const int ql = lane & 15, grp = lane >> 4;

  gemm_stage(gp, 0, As, Bs, tid);
  __syncthreads();  // drains the prologue stage

  const int nk = K / 32;
  for (int ks = 0; ks < nk; ks++) {
    __bf16* curA = As + (ks & 1) * TILE_E;
    __bf16* curB = Bs + (ks & 1) * TILE_E;
    if (ks + 1 < nk)  // issue next-tile loads BEFORE compute; they fly under it
      gemm_stage(gp, (ks + 1) * 32, As + ((ks + 1) & 1) * TILE_E,
                 Bs + ((ks + 1) & 1) * TILE_E, tid);

    bf16x8 af[4], bf_[4];
#pragma unroll
    for (int i = 0; i < 4; i++) {
      int row = wm * 64 + i * 16 + ql;
      int kc = grp ^ ((row >> 1) & 3);
      af[i] = *(const bf16x8*)(curA + row * 32 + kc * 8);
    }
#pragma unroll
    for (int j = 0; j < 4; j++) {
      int row = wn * 64 + j * 16 + ql;
      int kc = grp ^ ((row >> 1) & 3);
      bf_[j] = *(const bf16x8*)(curB + row * 32 + kc * 8);
    }
#pragma unroll
    for (int i = 0; i < 4; i++)
#pragma unroll
      for (int j = 0; j < 4; j++)
        acc[i][j] = mfma16(af[i], bf_[j], acc[i][j]);
    __syncthreads();  // waits vmcnt(0): next buffer staged; cur reads done
  }
}

__device__ __forceinline__ void gemm_store(f32x4 (*acc)[4], float* C, int N,
                                           int m0, int n0, int tid) {
  const int lane = tid & 63, w = tid >> 6;
  const int wm = w >> 1, wn = w & 1;
  const int ql = lane & 15, grp = lane >> 4;
#pragma unroll
  for (int i = 0; i < 4; i++)
#pragma unroll
    for (int j = 0; j < 4; j++)
#pragma unroll
      for (int r = 0; r < 4; r++) {
        int row = m0 + wm * 64 + i * 16 + grp * 4 + r;
        int col = n0 + wn * 64 + j * 16 + ql;
        C[(size_t)row * N + col] = acc[i][j][r];
      }
}

__device__ __forceinline__ void gemm_store_bf16(f32x4 (*acc)[4], __bf16* C, int N,
                                                int m0, int n0, int tid) {
  const int lane = tid & 63, w = tid >> 6;
  const int wm = w >> 1, wn = w & 1;
  const int ql = lane & 15, grp = lane >> 4;
#pragma unroll
  for (int i = 0; i < 4; i++)
#pragma unroll
    for (int j = 0; j < 4; j++)
#pragma unroll
      for (int r = 0; r < 4; r++) {
        int row = m0 + wm * 64 + i * 16 + grp * 4 + r;
        int col = n0 + wn * 64 + j * 16 + ql;
        C[(size_t)row * N + col] = (__bf16)acc[i][j][r];
      }
}

// ---------------- fused QKV GEMM: C(bf16) = X * [wq;wk;wv]^T ---------------
__global__ __launch_bounds__(256) void gemm_qkv(const __bf16* __restrict__ A,
                                                const __bf16* __restrict__ Wq,
                                                const __bf16* __restrict__ Wk,
                                                const __bf16* __restrict__ Wv,
                                                __bf16* __restrict__ C) {
  __shared__ __bf16 As[2 * TILE_E];
  __shared__ __bf16 Bs[2 * TILE_E];
  const int m0 = blockIdx.x * 128, n0 = blockIdx.y * 128;
  const __bf16* W;
  int nl;
  if (n0 < 768)       { W = Wq; nl = n0; }
  else if (n0 < 1024) { W = Wk; nl = n0 - 768; }
  else                { W = Wv; nl = n0 - 1024; }
  const int tid = threadIdx.x;
  f32x4 acc[4][4] = {};
  GemmPtrs gp = make_ptrs(A, W, m0, nl, 768, tid);
  gemm_core(gp, 768, As, Bs, tid, acc);
  gemm_store_bf16(acc, C, NQKV, m0, n0, tid);
}

// ------------------------- GEMM: C = A(bf16) * W^T -------------------------
__global__ __launch_bounds__(256) void gemm_xwT(const __bf16* __restrict__ A,
                                                const __bf16* __restrict__ W,
                                                float* __restrict__ C,
                                                int M, int N, int K) {
  __shared__ __bf16 As[2 * TILE_E];
  __shared__ __bf16 Bs[2 * TILE_E];
  const int m0 = blockIdx.x * 128, n0 = blockIdx.y * 128;
  const int tid = threadIdx.x;
  f32x4 acc[4][4] = {};
  GemmPtrs gp = make_ptrs(A, W, m0, n0, K, tid);
  gemm_core(gp, K, As, Bs, tid, acc);
  gemm_store(acc, C, N, m0, n0, tid);
}

// ------ vectorized RoPE (Q and K, one launch), bf16 in -> bf16 out ---------
// One thread = 4 RoPE pairs (8 bf16): bf16x8 load + float4 fc/fs + bf16x8
// store, all 16B coalesced. Q pre-scaled by (1/8)*log2(e).
__global__ void rope_both(const __bf16* __restrict__ QKV, const float* __restrict__ fc,
                          const float* __restrict__ fs, __bf16* __restrict__ Qb,
                          __bf16* __restrict__ Kb) {
  int idx = blockIdx.x * 256 + threadIdx.x;  // 8-element group index
  const int NQg = MROWS * NH_Q * 8;          // Q groups
  int NH, colOff;
  __bf16* dst;
  float scale;
  if (idx < NQg) {
    NH = NH_Q; colOff = 0; dst = Qb; scale = 0.125f * 1.44269504f;
  } else {
    idx -= NQg;
    if (idx >= MROWS * NKV_ * 8) return;
    NH = NKV_; colOff = 768; dst = Kb; scale = 1.0f;
  }
  const int g8 = idx & 7;            // 8-elem group within head (d = g8*8..+7)
  const int h = (idx >> 3) % NH;
  const int row = idx / (8 * NH);    // 0..8191
  const int s = row & (S_ - 1), b = row >> 11;

  bf16x8 v = *(const bf16x8*)(QKV + (size_t)row * NQKV + colOff + h * 64 + g8 * 8);
  f32x4 c4 = *(const f32x4*)(fc + s * 32 + g8 * 4);
  f32x4 s4 = *(const f32x4*)(fs + s * 32 + g8 * 4);
  bf16x8 o;
#pragma unroll
  for (int p = 0; p < 4; p++) {
    float x0 = (float)v[2 * p], x1 = (float)v[2 * p + 1];
    o[2 * p]     = (__bf16)((x0 * c4[p] - x1 * s4[p]) * scale);
    o[2 * p + 1] = (__bf16)((x0 * s4[p] + x1 * c4[p]) * scale);
  }
  *(bf16x8*)(dst + (((size_t)(b * NH + h) * S_ + s) << 6) + g8 * 8) = o;
}

// --------- V: cols [1024,1280) of (8192,1280) bf16 -> VT (B,4,64,2048) -----
__global__ void transpose_v(const __bf16* __restrict__ QKV, __bf16* __restrict__ VT) {
  __shared__ float tile[64][65];
  int rt = blockIdx.x;  // 0..127
  int ct = blockIdx.y;  // 0..3
  int r0 = rt * 64, c0 = ct * 64;
  int tx = threadIdx.x & 63, ty = threadIdx.x >> 6;
#pragma unroll
  for (int rep = 0; rep < 16; rep++) {
    int rr = rep * 4 + ty;
    tile[rr][tx] = (float)QKV[(size_t)(r0 + rr) * NQKV + 1024 + c0 + tx];
  }
  __syncthreads();
  int b = r0 >> 11;
  int s0 = r0 & (S_ - 1);
#pragma unroll
  for (int rep = 0; rep < 16; rep++) {
    int dr = rep * 4 + ty;
    int d = c0 + dr;
    int kv = d >> 6, dd = d & 63;
    VT[(((size_t)(b * NKV_ + kv) * 64 + dd) * S_) + s0 + tx] = (__bf16)tile[tx][dr];
  }
}

// ------------------------------- attention ---------------------------------
// R7 structure (best measured): single-pass, P in registers (packed bf16);
// phase 1 = QK^T+exp2; barrier; phase 2 = V loads + shfl + PV MFMA + attn
// stores. XCD-grouped 1-D grid keeps each (h,b)'s K/V L2-resident.
template <int MAXC>
__device__ __forceinline__ void attn_part(
    int g, int b, int h, int w, int lane,
    const __bf16* __restrict__ Q, const __bf16* __restrict__ Kp,
    const __bf16* __restrict__ Vp, float* __restrict__ attn,
    __bf16* __restrict__ O, float (*lsum_s)[16], f32x4 (*obuf)[4]) {
  const int ql = lane & 15, grp = lane >> 4;
  const int qr0 = g * 16;
  const int nch = (g >> 1) + 1;
  const int i_q = qr0 + ql;
  const __bf16* Qp = Q + ((size_t)(b * NH_Q + h) * S_ + qr0) * 64;
  float* attnp = attn + ((size_t)(b * NH_Q + h) * S_ + qr0) * S_;

  bf16x8 bq0 = *(const bf16x8*)(Qp + ql * 64 + grp * 8);
  bf16x8 bq1 = *(const bf16x8*)(Qp + ql * 64 + 32 + grp * 8);

  uint32_t p[MAXC][4];
  float lsum = 0.f;

  // ---- phase 1: QK^T + exp2, P -> registers (packed bf16) ----
#pragma unroll
  for (int c = 0; c < MAXC; c++) {
    const int j = w + 4 * c;
    if (j < nch) {
      const int j0 = j * 32;
      bf16x8 k0 = *(const bf16x8*)(Kp + (size_t)(j0 + ql) * 64 + grp * 8);
      bf16x8 k1 = *(const bf16x8*)(Kp + (size_t)(j0 + ql) * 64 + 32 + grp * 8);
      bf16x8 k2 = *(const bf16x8*)(Kp + (size_t)(j0 + 16 + ql) * 64 + grp * 8);
      bf16x8 k3 = *(const bf16x8*)(Kp + (size_t)(j0 + 16 + ql) * 64 + 32 + grp * 8);
      f32x4 s0 = {}, s1 = {};
      s0 = mfma16(k0, bq0, s0);
      s0 = mfma16(k1, bq1, s0);
      s1 = mfma16(k2, bq0, s1);
      s1 = mfma16(k3, bq1, s1);
      float e[8];
      if (j == nch - 1) {  // only the last chunk is causally masked
#pragma unroll
        for (int r = 0; r < 4; r++) {
          int ja = j0 + grp * 4 + r, jb = j0 + 16 + grp * 4 + r;
          e[r]     = (ja <= i_q) ? exp2f(s0[r]) : 0.f;
          e[4 + r] = (jb <= i_q) ? exp2f(s1[r]) : 0.f;
        }
      } else {
#pragma unroll
        for (int r = 0; r < 4; r++) {
          e[r]     = exp2f(s0[r]);
          e[4 + r] = exp2f(s1[r]);
        }
      }
#pragma unroll
      for (int r = 0; r < 8; r++) lsum += e[r];
      p[c][0] = pk2(e[0], e[1]);
      p[c][1] = pk2(e[2], e[3]);
      p[c][2] = pk2(e[4], e[5]);
      p[c][3] = pk2(e[6], e[7]);
    }
  }

  // ---- cross-lane + cross-wave row-sum ----
  lsum += __shfl_xor(lsum, 16);
  lsum += __shfl_xor(lsum, 32);
  if (lane < 16) lsum_s[w][ql] = lsum;
  __syncthreads();
  const float rinv = 1.f / (lsum_s[0][ql] + lsum_s[1][ql] + lsum_s[2][ql] + lsum_s[3][ql]);

  // ---- phase 2: normalize+write attn, PV MFMA ----
  f32x4 opv[4] = {};
#pragma unroll
  for (int c = 0; c < MAXC; c++) {
    const int j = w + 4 * c;
    if (j < nch) {
      const int j0 = j * 32;
      bf16x8 v0 = *(const bf16x8*)(Vp + (size_t)(0 * 16 + ql) * S_ + j0 + grp * 8);
      bf16x8 v1 = *(const bf16x8*)(Vp + (size_t)(1 * 16 + ql) * S_ + j0 + grp * 8);
      bf16x8 v2 = *(const bf16x8*)(Vp + (size_t)(2 * 16 + ql) * S_ + j0 + grp * 8);
      bf16x8 v3 = *(const bf16x8*)(Vp + (size_t)(3 * 16 + ql) * S_ + j0 + grp * 8);

      f32x4 q0, q1;
      q0[0] = bl(p[c][0]); q0[1] = bh(p[c][0]); q0[2] = bl(p[c][1]); q0[3] = bh(p[c][1]);
      q1[0] = bl(p[c][2]); q1[1] = bh(p[c][2]); q1[2] = bl(p[c][3]); q1[3] = bh(p[c][3]);
#pragma unroll
      for (int r = 0; r < 4; r++) { q0[r] *= rinv; q1[r] *= rinv; }
      st_nt4(attnp + (size_t)ql * S_ + j0 + grp * 4, q0);
      st_nt4(attnp + (size_t)ql * S_ + j0 + 16 + grp * 4, q1);

      int srcA = ql + 32 * (grp & 1);
      int srcB = srcA + 16;
      uint32_t A0 = __shfl(p[c][0], srcA), A1 = __shfl(p[c][1], srcA);
      uint32_t A2 = __shfl(p[c][2], srcA), A3 = __shfl(p[c][3], srcA);
      uint32_t B0 = __shfl(p[c][0], srcB), B1 = __shfl(p[c][1], srcB);
      uint32_t B2 = __shfl(p[c][2], srcB), B3 = __shfl(p[c][3], srcB);
      bool hi = (grp >> 1) != 0;
      union { bf16x8 v; uint32_t u[4]; } pu;
      pu.u[0] = hi ? A2 : A0;
      pu.u[1] = hi ? A3 : A1;
      pu.u[2] = hi ? B2 : B0;
      pu.u[3] = hi ? B3 : B1;
      opv[0] = mfma16(pu.v, v0, opv[0]);
      opv[1] = mfma16(pu.v, v1, opv[1]);
      opv[2] = mfma16(pu.v, v2, opv[2]);
      opv[3] = mfma16(pu.v, v3, opv[3]);
    }
  }

  // ---- cross-wave O reduce + write (unnormalized opv; scale by row rinv) ----
  f32x4* ob = obuf[w * 64 + lane];
  ob[0] = opv[0]; ob[1] = opv[1]; ob[2] = opv[2]; ob[3] = opv[3];
  __syncthreads();
  {
    const int dt = w;
    f32x4 acc = obuf[0 * 64 + lane][dt];
    acc += obuf[1 * 64 + lane][dt];
    acc += obuf[2 * 64 + lane][dt];
    acc += obuf[3 * 64 + lane][dt];
    __bf16* Op = O + ((size_t)(b * S_) + qr0) * H_ + h * 64;
#pragma unroll
    for (int r = 0; r < 4; r++) {
      int row = grp * 4 + r;
      float rr = 1.f / (lsum_s[0][row] + lsum_s[1][row] + lsum_s[2][row] + lsum_s[3][row]);
      Op[(size_t)row * H_ + dt * 16 + ql] = (__bf16)(acc[r] * rr);
    }
  }

  // ---- zero causal tail [nch*32, S) cooperatively (256 threads) ----
  const int jz = nch * 32;
  const int tid = w * 64 + lane;
  const f32x4 z4 = {0.f, 0.f, 0.f, 0.f};
#pragma unroll 1
  for (int rr = 0; rr < 16; rr++) {
    float* rowp = attnp + (size_t)rr * S_;
    for (int jj = jz + tid * 4; jj < S_; jj += 1024) st_nt4(rowp + jj, z4);
  }
  __syncthreads();  // protect lsum_s/obuf for the next part
}

__global__ __launch_bounds__(256) void attn_kernel(const __bf16* __restrict__ Q,
                                                   const __bf16* __restrict__ Kb,
                                                   const __bf16* __restrict__ VT,
                                                   float* __restrict__ attn,
                                                   __bf16* __restrict__ O) {
  __shared__ float lsum_s[4][16];
  __shared__ f32x4 obuf[4 * 64][4];
  // XCD-grouping decode (bijective): bid = r + 8*(x + 64*idx6),
  // g48 = idx6*8 + r -> (h,b); all blocks of one (h,b) share bid%8 -> one XCD.
  const int bid = blockIdx.x;
  const int r = bid & 7;
  const int qd = bid >> 3;
  const int x = qd & 63;
  const int idx6 = qd >> 6;        // 0..5
  const int g48 = idx6 * 8 + r;    // 0..47
  const int h = g48 >> 2, b = g48 & 3;
  const int lane = threadIdx.x & 63, w = threadIdx.x >> 6;
  const int kv = h / 3;
  const __bf16* Kp = Kb + (size_t)(b * NKV_ + kv) * S_ * 64;
  const __bf16* Vp = VT + (size_t)(b * NKV_ + kv) * 64 * S_;

  attn_part<8>(x, b, h, w, lane, Q, Kp, Vp, attn, O, lsum_s, obuf);        // g = 0..63
  attn_part<16>(127 - x, b, h, w, lane, Q, Kp, Vp, attn, O, lsum_s, obuf); // g = 64..127
}

// ---------------------------------------------------------------------------
extern "C" void kernel_launch(void* const* d_in, const int* in_sizes, int n_in,
                              void* d_out, int out_size, void* d_ws, size_t ws_size,
                              hipStream_t stream) {
  (void)in_sizes; (void)n_in;
  const float* X  = (const float*)d_in[0];
  const float* fc = (const float*)d_in[1];
  const float* fs = (const float*)d_in[2];
  const float* wq = (const float*)d_in[3];
  const float* wk = (const float*)d_in[4];
  const float* wv = (const float*)d_in[5];
  const float* wo = (const float*)d_in[6];
  float* out0 = (float*)d_out;
  float* attn = out0 + (size_t)B_ * S_ * H_;

  // ---- scratch layout ----
  char* p = (char*)d_ws;
  auto take = [&](size_t bytes) -> char* {
    char* r = p;
    p += (bytes + 255) & ~(size_t)255;
    return r;
  };
  __bf16* wqbf = (__bf16*)take((size_t)768 * 768 * 2);
  __bf16* wkbf = (__bf16*)take((size_t)256 * 768 * 2);
  __bf16* wvbf = (__bf16*)take((size_t)256 * 768 * 2);
  __bf16* wobf = (__bf16*)take((size_t)768 * 768 * 2);
  __bf16* Qbf  = (__bf16*)take((size_t)MROWS * 768 * 2);
  __bf16* Kbf  = (__bf16*)take((size_t)MROWS * 256 * 2);
  __bf16* VTbf = (__bf16*)take((size_t)MROWS * 256 * 2);
  __bf16* Obf  = (__bf16*)take((size_t)MROWS * 768 * 2);
  size_t used = (size_t)(p - (char*)d_ws);

  const size_t XBF_B  = (size_t)MROWS * 768 * 2;
  const size_t QKV_B  = (size_t)MROWS * NQKV * 2;  // bf16 now
  const size_t TEMP_B = XBF_B + QKV_B;

  char* tp;
  if (used + TEMP_B + 1024 <= ws_size) {
    tp = p;
  } else {
    // tail of the attn output region; fully consumed before attn_kernel writes
    tp = (char*)(((uintptr_t)((char*)d_out + (size_t)out_size * 4 - TEMP_B)) & ~(uintptr_t)255);
  }
  __bf16* Xbf  = (__bf16*)tp;  tp += XBF_B;
  __bf16* QKVb = (__bf16*)tp;

  // ---- 1. fused casts (one launch) ----
  {
    const int total8 = MROWS * 768 / 8 + 2 * (768 * 768 / 8) + 2 * (256 * 768 / 8);
    cast_all<<<(total8 + 255) / 256, 256, 0, stream>>>(X, wq, wo, wk, wv,
                                                       Xbf, wqbf, wobf, wkbf, wvbf);
  }

  // ---- 2. fused QKV projection (bf16 output, 2-phase dbuf) ----
  gemm_qkv<<<dim3(MROWS / 128, NQKV / 128), 256, 0, stream>>>(Xbf, wqbf, wkbf, wvbf, QKVb);

  // ---- 3. vectorized RoPE (Q+K) + V transpose, both bf16 in ----
  {
    const int totalG = MROWS * NH_Q * 8 + MROWS * NKV_ * 8;  // 1048576
    rope_both<<<(totalG + 255) / 256, 256, 0, stream>>>(QKVb, fc, fs, Qbf, Kbf);
  }
  transpose_v<<<dim3(MROWS / 64, 4), 256, 0, stream>>>(QKVb, VTbf);

  // ---- 4. attention (writes attn fp32 + Obf bf16) ----
  attn_kernel<<<dim3(48 * 64), 256, 0, stream>>>(Qbf, Kbf, VTbf, attn, Obf);

  // ---- 5. output projection ----
  gemm_xwT<<<dim3(MROWS / 128, 768 / 128), 256, 0, stream>>>(Obf, wobf, out0, MROWS, 768, 768);
}

// Round 16
// 286.263 us; speedup vs baseline: 1.0451x; 1.0028x over previous
//
#include <hip/hip_runtime.h>
#include <hip/hip_bf16.h>
#include <stdint.h>

// ---------------------------------------------------------------------------
// TinyLlamaGQA: B=4 S=2048 H=768 NH=12 NKV=4 D=64
// outputs: out0 (B,S,768) fp32  then attn (B,12,S,S) fp32, concatenated flat.
// ---------------------------------------------------------------------------

typedef __bf16 bf16x8 __attribute__((ext_vector_type(8)));
typedef float  f32x4  __attribute__((ext_vector_type(4)));

#define B_    4
#define S_    2048
#define H_    768
#define NH_Q  12
#define NKV_  4
#define D_    64
#define MROWS (B_ * S_)   // 8192
#define NQKV  1280        // 768 + 256 + 256
#define TILE_E (128 * 32) // LDS tile elements per buffer

__device__ __forceinline__ f32x4 mfma16(bf16x8 a, bf16x8 b, f32x4 c) {
  return __builtin_amdgcn_mfma_f32_16x16x32_bf16(a, b, c, 0, 0, 0);
}

__device__ __forceinline__ void st_nt4(float* p, f32x4 v) {
  __builtin_nontemporal_store(v, (f32x4*)p);
}

__device__ __forceinline__ uint32_t pk2(float a, float b) {
  __bf16 x = (__bf16)a, y = (__bf16)b;
  uint16_t xu = __builtin_bit_cast(uint16_t, x);
  uint16_t yu = __builtin_bit_cast(uint16_t, y);
  return (uint32_t)xu | ((uint32_t)yu << 16);
}
__device__ __forceinline__ float bl(uint32_t u) {
  uint32_t t = u << 16; return __builtin_bit_cast(float, t);
}
__device__ __forceinline__ float bh(uint32_t u) {
  uint32_t t = u & 0xffff0000u; return __builtin_bit_cast(float, t);
}

// async global->LDS, 16B/lane; LDS dest is wave-uniform base + lane*16.
__device__ __forceinline__ void gload_lds16(const __bf16* g, __bf16* l) {
  __builtin_amdgcn_global_load_lds(
      (const __attribute__((address_space(1))) void*)g,
      (__attribute__((address_space(3))) void*)l, 16, 0, 0);
}

// ----------------- fused cast fp32 -> bf16 (all 5 tensors) -----------------
__global__ void cast_all(const float* __restrict__ X, const float* __restrict__ wq,
                         const float* __restrict__ wo, const float* __restrict__ wk,
                         const float* __restrict__ wv,
                         __bf16* __restrict__ Xb, __bf16* __restrict__ wqb,
                         __bf16* __restrict__ wob, __bf16* __restrict__ wkb,
                         __bf16* __restrict__ wvb) {
  int i = blockIdx.x * 256 + threadIdx.x;  // 8-element item
  const int nX = MROWS * 768 / 8;   // 786432
  const int nW = 768 * 768 / 8;     // 73728
  const int nK = 256 * 768 / 8;     // 24576
  const float* s; __bf16* d; int off;
  if (i < nX)                    { s = X;  d = Xb;  off = i; }
  else if (i < nX + nW)          { s = wq; d = wqb; off = i - nX; }
  else if (i < nX + 2 * nW)      { s = wo; d = wob; off = i - nX - nW; }
  else if (i < nX + 2 * nW + nK) { s = wk; d = wkb; off = i - nX - 2 * nW; }
  else if (i < nX + 2 * nW + 2 * nK) { s = wv; d = wvb; off = i - nX - 2 * nW - nK; }
  else return;
  const float4* sp = (const float4*)s + (size_t)off * 2;
  float4 a = sp[0], b = sp[1];
  bf16x8 o;
  o[0] = (__bf16)a.x; o[1] = (__bf16)a.y; o[2] = (__bf16)a.z; o[3] = (__bf16)a.w;
  o[4] = (__bf16)b.x; o[5] = (__bf16)b.y; o[6] = (__bf16)b.z; o[7] = (__bf16)b.w;
  *((bf16x8*)d + off) = o;
}

// ------------------------- GEMM core (2-phase dbuf) ------------------------
struct GemmPtrs {
  const __bf16 *gA0, *gA1, *gB0, *gB1;
};

__device__ __forceinline__ GemmPtrs make_ptrs(const __bf16* A, const __bf16* W,
                                              int m0, int n0, int K, int tid) {
  GemmPtrs gp;
  int c0 = tid, c1 = 256 + tid;
  int sr0 = c0 >> 2, kc0 = (c0 & 3) ^ ((sr0 >> 1) & 3);
  int sr1 = c1 >> 2, kc1 = (c1 & 3) ^ ((sr1 >> 1) & 3);
  gp.gA0 = A + (size_t)(m0 + sr0) * K + kc0 * 8;
  gp.gA1 = A + (size_t)(m0 + sr1) * K + kc1 * 8;
  gp.gB0 = W + (size_t)(n0 + sr0) * K + kc0 * 8;
  gp.gB1 = W + (size_t)(n0 + sr1) * K + kc1 * 8;
  return gp;
}

__device__ __forceinline__ void gemm_stage(GemmPtrs gp, int k0,
                                           __bf16* As, __bf16* Bs, int tid) {
  __bf16* lA0 = As + (size_t)(tid & ~63) * 8;
  __bf16* lB0 = Bs + (size_t)(tid & ~63) * 8;
  gload_lds16(gp.gA0 + k0, lA0);
  gload_lds16(gp.gA1 + k0, lA0 + 256 * 8);
  gload_lds16(gp.gB0 + k0, lB0);
  gload_lds16(gp.gB1 + k0, lB0 + 256 * 8);
}

__device__ __forceinline__ void gemm_core(GemmPtrs gp, int K,
                                          __bf16* As, __bf16* Bs,
                                          int tid, f32x4 (*acc)[4]) {
  const int lane = tid & 63, w = tid >> 6;
  const int wm = w >> 1, wn = w & 1;
  const int ql = lane & 15, grp = lane >> 4;

  gemm_stage(gp, 0, As, Bs, tid);
  __syncthreads();  // drains the prologue stage

  const int nk = K / 32;
  for (int ks = 0; ks < nk; ks++) {
    __bf16* curA = As + (ks & 1) * TILE_E;
    __bf16* curB = Bs + (ks & 1) * TILE_E;
    if (ks + 1 < nk)  // issue next-tile loads BEFORE compute; they fly under it
      gemm_stage(gp, (ks + 1) * 32, As + ((ks + 1) & 1) * TILE_E,
                 Bs + ((ks + 1) & 1) * TILE_E, tid);

    bf16x8 af[4], bf_[4];
#pragma unroll
    for (int i = 0; i < 4; i++) {
      int row = wm * 64 + i * 16 + ql;
      int kc = grp ^ ((row >> 1) & 3);
      af[i] = *(const bf16x8*)(curA + row * 32 + kc * 8);
    }
#pragma unroll
    for (int j = 0; j < 4; j++) {
      int row = wn * 64 + j * 16 + ql;
      int kc = grp ^ ((row >> 1) & 3);
      bf_[j] = *(const bf16x8*)(curB + row * 32 + kc * 8);
    }
#pragma unroll
    for (int i = 0; i < 4; i++)
#pragma unroll
      for (int j = 0; j < 4; j++)
        acc[i][j] = mfma16(af[i], bf_[j], acc[i][j]);
    __syncthreads();  // waits vmcnt(0): next buffer staged; cur reads done
  }
}

__device__ __forceinline__ void gemm_store(f32x4 (*acc)[4], float* C, int N,
                                           int m0, int n0, int tid) {
  const int lane = tid & 63, w = tid >> 6;
  const int wm = w >> 1, wn = w & 1;
  const int ql = lane & 15, grp = lane >> 4;
#pragma unroll
  for (int i = 0; i < 4; i++)
#pragma unroll
    for (int j = 0; j < 4; j++)
#pragma unroll
      for (int r = 0; r < 4; r++) {
        int row = m0 + wm * 64 + i * 16 + grp * 4 + r;
        int col = n0 + wn * 64 + j * 16 + ql;
        C[(size_t)row * N + col] = acc[i][j][r];
      }
}

__device__ __forceinline__ void gemm_store_bf16(f32x4 (*acc)[4], __bf16* C, int N,
                                                int m0, int n0, int tid) {
  const int lane = tid & 63, w = tid >> 6;
  const int wm = w >> 1, wn = w & 1;
  const int ql = lane & 15, grp = lane >> 4;
#pragma unroll
  for (int i = 0; i < 4; i++)
#pragma unroll
    for (int j = 0; j < 4; j++)
#pragma unroll
      for (int r = 0; r < 4; r++) {
        int row = m0 + wm * 64 + i * 16 + grp * 4 + r;
        int col = n0 + wn * 64 + j * 16 + ql;
        C[(size_t)row * N + col] = (__bf16)acc[i][j][r];
      }
}

// ---------------- fused QKV GEMM: C(bf16) = X * [wq;wk;wv]^T ---------------
__global__ __launch_bounds__(256) void gemm_qkv(const __bf16* __restrict__ A,
                                                const __bf16* __restrict__ Wq,
                                                const __bf16* __restrict__ Wk,
                                                const __bf16* __restrict__ Wv,
                                                __bf16* __restrict__ C) {
  __shared__ __bf16 As[2 * TILE_E];
  __shared__ __bf16 Bs[2 * TILE_E];
  const int m0 = blockIdx.x * 128, n0 = blockIdx.y * 128;
  const __bf16* W;
  int nl;
  if (n0 < 768)       { W = Wq; nl = n0; }
  else if (n0 < 1024) { W = Wk; nl = n0 - 768; }
  else                { W = Wv; nl = n0 - 1024; }
  const int tid = threadIdx.x;
  f32x4 acc[4][4] = {};
  GemmPtrs gp = make_ptrs(A, W, m0, nl, 768, tid);
  gemm_core(gp, 768, As, Bs, tid, acc);
  gemm_store_bf16(acc, C, NQKV, m0, n0, tid);
}

// ------------------------- GEMM: C = A(bf16) * W^T -------------------------
__global__ __launch_bounds__(256) void gemm_xwT(const __bf16* __restrict__ A,
                                                const __bf16* __restrict__ W,
                                                float* __restrict__ C,
                                                int M, int N, int K) {
  __shared__ __bf16 As[2 * TILE_E];
  __shared__ __bf16 Bs[2 * TILE_E];
  const int m0 = blockIdx.x * 128, n0 = blockIdx.y * 128;
  const int tid = threadIdx.x;
  f32x4 acc[4][4] = {};
  GemmPtrs gp = make_ptrs(A, W, m0, n0, K, tid);
  gemm_core(gp, K, As, Bs, tid, acc);
  gemm_store(acc, C, N, m0, n0, tid);
}

// ------ vectorized RoPE (Q and K, one launch), bf16 in -> bf16 out ---------
__global__ void rope_both(const __bf16* __restrict__ QKV, const float* __restrict__ fc,
                          const float* __restrict__ fs, __bf16* __restrict__ Qb,
                          __bf16* __restrict__ Kb) {
  int idx = blockIdx.x * 256 + threadIdx.x;  // 8-element group index
  const int NQg = MROWS * NH_Q * 8;          // Q groups
  int NH, colOff;
  __bf16* dst;
  float scale;
  if (idx < NQg) {
    NH = NH_Q; colOff = 0; dst = Qb; scale = 0.125f * 1.44269504f;
  } else {
    idx -= NQg;
    if (idx >= MROWS * NKV_ * 8) return;
    NH = NKV_; colOff = 768; dst = Kb; scale = 1.0f;
  }
  const int g8 = idx & 7;            // 8-elem group within head (d = g8*8..+7)
  const int h = (idx >> 3) % NH;
  const int row = idx / (8 * NH);    // 0..8191
  const int s = row & (S_ - 1), b = row >> 11;

  bf16x8 v = *(const bf16x8*)(QKV + (size_t)row * NQKV + colOff + h * 64 + g8 * 8);
  f32x4 c4 = *(const f32x4*)(fc + s * 32 + g8 * 4);
  f32x4 s4 = *(const f32x4*)(fs + s * 32 + g8 * 4);
  bf16x8 o;
#pragma unroll
  for (int p = 0; p < 4; p++) {
    float x0 = (float)v[2 * p], x1 = (float)v[2 * p + 1];
    o[2 * p]     = (__bf16)((x0 * c4[p] - x1 * s4[p]) * scale);
    o[2 * p + 1] = (__bf16)((x0 * s4[p] + x1 * c4[p]) * scale);
  }
  *(bf16x8*)(dst + (((size_t)(b * NH + h) * S_ + s) << 6) + g8 * 8) = o;
}

// --------- V: cols [1024,1280) of (8192,1280) bf16 -> VT (B,4,64,2048) -----
__global__ void transpose_v(const __bf16* __restrict__ QKV, __bf16* __restrict__ VT) {
  __shared__ float tile[64][65];
  int rt = blockIdx.x;  // 0..127
  int ct = blockIdx.y;  // 0..3
  int r0 = rt * 64, c0 = ct * 64;
  int tx = threadIdx.x & 63, ty = threadIdx.x >> 6;
#pragma unroll
  for (int rep = 0; rep < 16; rep++) {
    int rr = rep * 4 + ty;
    tile[rr][tx] = (float)QKV[(size_t)(r0 + rr) * NQKV + 1024 + c0 + tx];
  }
  __syncthreads();
  int b = r0 >> 11;
  int s0 = r0 & (S_ - 1);
#pragma unroll
  for (int rep = 0; rep < 16; rep++) {
    int dr = rep * 4 + ty;
    int d = c0 + dr;
    int kv = d >> 6, dd = d & 63;
    VT[(((size_t)(b * NKV_ + kv) * 64 + dd) * S_) + s0 + tx] = (__bf16)tile[tx][dr];
  }
}

// ------------------------------- attention ---------------------------------
// 8-wave (512-thread) variant of the R7/R15 structure: each block owns the
// complementary q-group pair (x, 127-x); the 8 waves split a group's chunks
// round-robin (j = w + 8c). Halves per-wave serial chain AND P register
// footprint vs the 4-wave version -> more resident waves, more outstanding
// stores. XCD-grouped 1-D grid keeps each (h,b)'s K/V L2-resident.
template <int MAXC>
__device__ __forceinline__ void attn_part(
    int g, int b, int h, int w, int lane,
    const __bf16* __restrict__ Q, const __bf16* __restrict__ Kp,
    const __bf16* __restrict__ Vp, float* __restrict__ attn,
    __bf16* __restrict__ O, float (*lsum_s)[16], f32x4 (*obuf)[4]) {
  const int ql = lane & 15, grp = lane >> 4;
  const int qr0 = g * 16;
  const int nch = (g >> 1) + 1;
  const int i_q = qr0 + ql;
  const __bf16* Qp = Q + ((size_t)(b * NH_Q + h) * S_ + qr0) * 64;
  float* attnp = attn + ((size_t)(b * NH_Q + h) * S_ + qr0) * S_;

  bf16x8 bq0 = *(const bf16x8*)(Qp + ql * 64 + grp * 8);
  bf16x8 bq1 = *(const bf16x8*)(Qp + ql * 64 + 32 + grp * 8);

  uint32_t p[MAXC][4];
  float lsum = 0.f;

  // ---- phase 1: QK^T + exp2, P -> registers (packed bf16) ----
#pragma unroll
  for (int c = 0; c < MAXC; c++) {
    const int j = w + 8 * c;
    if (j < nch) {
      const int j0 = j * 32;
      bf16x8 k0 = *(const bf16x8*)(Kp + (size_t)(j0 + ql) * 64 + grp * 8);
      bf16x8 k1 = *(const bf16x8*)(Kp + (size_t)(j0 + ql) * 64 + 32 + grp * 8);
      bf16x8 k2 = *(const bf16x8*)(Kp + (size_t)(j0 + 16 + ql) * 64 + grp * 8);
      bf16x8 k3 = *(const bf16x8*)(Kp + (size_t)(j0 + 16 + ql) * 64 + 32 + grp * 8);
      f32x4 s0 = {}, s1 = {};
      s0 = mfma16(k0, bq0, s0);
      s0 = mfma16(k1, bq1, s0);
      s1 = mfma16(k2, bq0, s1);
      s1 = mfma16(k3, bq1, s1);
      float e[8];
      if (j == nch - 1) {  // only the last chunk is causally masked
#pragma unroll
        for (int r = 0; r < 4; r++) {
          int ja = j0 + grp * 4 + r, jb = j0 + 16 + grp * 4 + r;
          e[r]     = (ja <= i_q) ? exp2f(s0[r]) : 0.f;
          e[4 + r] = (jb <= i_q) ? exp2f(s1[r]) : 0.f;
        }
      } else {
#pragma unroll
        for (int r = 0; r < 4; r++) {
          e[r]     = exp2f(s0[r]);
          e[4 + r] = exp2f(s1[r]);
        }
      }
#pragma unroll
      for (int r = 0; r < 8; r++) lsum += e[r];
      p[c][0] = pk2(e[0], e[1]);
      p[c][1] = pk2(e[2], e[3]);
      p[c][2] = pk2(e[4], e[5]);
      p[c][3] = pk2(e[6], e[7]);
    }
  }

  // ---- cross-lane + cross-wave row-sum ----
  lsum += __shfl_xor(lsum, 16);
  lsum += __shfl_xor(lsum, 32);
  if (lane < 16) lsum_s[w][ql] = lsum;
  __syncthreads();
  const float rinv = 1.f / (lsum_s[0][ql] + lsum_s[1][ql] + lsum_s[2][ql] + lsum_s[3][ql] +
                            lsum_s[4][ql] + lsum_s[5][ql] + lsum_s[6][ql] + lsum_s[7][ql]);

  // ---- phase 2: normalize+write attn, PV MFMA ----
  f32x4 opv[4] = {};
#pragma unroll
  for (int c = 0; c < MAXC; c++) {
    const int j = w + 8 * c;
    if (j < nch) {
      const int j0 = j * 32;
      bf16x8 v0 = *(const bf16x8*)(Vp + (size_t)(0 * 16 + ql) * S_ + j0 + grp * 8);
      bf16x8 v1 = *(const bf16x8*)(Vp + (size_t)(1 * 16 + ql) * S_ + j0 + grp * 8);
      bf16x8 v2 = *(const bf16x8*)(Vp + (size_t)(2 * 16 + ql) * S_ + j0 + grp * 8);
      bf16x8 v3 = *(const bf16x8*)(Vp + (size_t)(3 * 16 + ql) * S_ + j0 + grp * 8);

      f32x4 q0, q1;
      q0[0] = bl(p[c][0]); q0[1] = bh(p[c][0]); q0[2] = bl(p[c][1]); q0[3] = bh(p[c][1]);
      q1[0] = bl(p[c][2]); q1[1] = bh(p[c][2]); q1[2] = bl(p[c][3]); q1[3] = bh(p[c][3]);
#pragma unroll
      for (int r = 0; r < 4; r++) { q0[r] *= rinv; q1[r] *= rinv; }
      st_nt4(attnp + (size_t)ql * S_ + j0 + grp * 4, q0);
      st_nt4(attnp + (size_t)ql * S_ + j0 + 16 + grp * 4, q1);

      int srcA = ql + 32 * (grp & 1);
      int srcB = srcA + 16;
      uint32_t A0 = __shfl(p[c][0], srcA), A1 = __shfl(p[c][1], srcA);
      uint32_t A2 = __shfl(p[c][2], srcA), A3 = __shfl(p[c][3], srcA);
      uint32_t B0 = __shfl(p[c][0], srcB), B1 = __shfl(p[c][1], srcB);
      uint32_t B2 = __shfl(p[c][2], srcB), B3 = __shfl(p[c][3], srcB);
      bool hi = (grp >> 1) != 0;
      union { bf16x8 v; uint32_t u[4]; } pu;
      pu.u[0] = hi ? A2 : A0;
      pu.u[1] = hi ? A3 : A1;
      pu.u[2] = hi ? B2 : B0;
      pu.u[3] = hi ? B3 : B1;
      opv[0] = mfma16(pu.v, v0, opv[0]);
      opv[1] = mfma16(pu.v, v1, opv[1]);
      opv[2] = mfma16(pu.v, v2, opv[2]);
      opv[3] = mfma16(pu.v, v3, opv[3]);
    }
  }

  // ---- cross-wave O reduce (8 partials) + write ----
  f32x4* ob = obuf[w * 64 + lane];
  ob[0] = opv[0]; ob[1] = opv[1]; ob[2] = opv[2]; ob[3] = opv[3];
  __syncthreads();
  if (w < 4) {
    const int dt = w;
    f32x4 acc = obuf[0 * 64 + lane][dt];
#pragma unroll
    for (int k = 1; k < 8; k++) acc += obuf[k * 64 + lane][dt];
    __bf16* Op = O + ((size_t)(b * S_) + qr0) * H_ + h * 64;
#pragma unroll
    for (int r = 0; r < 4; r++) {
      int row = grp * 4 + r;
      float rr = 1.f / (lsum_s[0][row] + lsum_s[1][row] + lsum_s[2][row] + lsum_s[3][row] +
                        lsum_s[4][row] + lsum_s[5][row] + lsum_s[6][row] + lsum_s[7][row]);
      Op[(size_t)row * H_ + dt * 16 + ql] = (__bf16)(acc[r] * rr);
    }
  }

  // ---- zero causal tail [nch*32, S) cooperatively (512 threads) ----
  const int jz = nch * 32;
  const int tid = w * 64 + lane;
  const f32x4 z4 = {0.f, 0.f, 0.f, 0.f};
#pragma unroll 1
  for (int rr = 0; rr < 16; rr++) {
    float* rowp = attnp + (size_t)rr * S_;
    for (int jj = jz + tid * 4; jj < S_; jj += 2048) st_nt4(rowp + jj, z4);
  }
  __syncthreads();  // protect lsum_s/obuf for the next part
}

__global__ __launch_bounds__(512) void attn_kernel(const __bf16* __restrict__ Q,
                                                   const __bf16* __restrict__ Kb,
                                                   const __bf16* __restrict__ VT,
                                                   float* __restrict__ attn,
                                                   __bf16* __restrict__ O) {
  __shared__ float lsum_s[8][16];
  __shared__ f32x4 obuf[8 * 64][4];
  // XCD-grouping decode (bijective): bid = r + 8*(x + 64*idx6),
  // g48 = idx6*8 + r -> (h,b); all blocks of one (h,b) share bid%8 -> one XCD.
  const int bid = blockIdx.x;
  const int r = bid & 7;
  const int qd = bid >> 3;
  const int x = qd & 63;
  const int idx6 = qd >> 6;        // 0..5
  const int g48 = idx6 * 8 + r;    // 0..47
  const int h = g48 >> 2, b = g48 & 3;
  const int lane = threadIdx.x & 63, w = threadIdx.x >> 6;  // w = 0..7
  const int kv = h / 3;
  const __bf16* Kp = Kb + (size_t)(b * NKV_ + kv) * S_ * 64;
  const __bf16* Vp = VT + (size_t)(b * NKV_ + kv) * 64 * S_;

  attn_part<4>(x, b, h, w, lane, Q, Kp, Vp, attn, O, lsum_s, obuf);        // g = 0..63
  attn_part<8>(127 - x, b, h, w, lane, Q, Kp, Vp, attn, O, lsum_s, obuf);  // g = 64..127
}

// ---------------------------------------------------------------------------
extern "C" void kernel_launch(void* const* d_in, const int* in_sizes, int n_in,
                              void* d_out, int out_size, void* d_ws, size_t ws_size,
                              hipStream_t stream) {
  (void)in_sizes; (void)n_in;
  const float* X  = (const float*)d_in[0];
  const float* fc = (const float*)d_in[1];
  const float* fs = (const float*)d_in[2];
  const float* wq = (const float*)d_in[3];
  const float* wk = (const float*)d_in[4];
  const float* wv = (const float*)d_in[5];
  const float* wo = (const float*)d_in[6];
  float* out0 = (float*)d_out;
  float* attn = out0 + (size_t)B_ * S_ * H_;

  // ---- scratch layout ----
  char* p = (char*)d_ws;
  auto take = [&](size_t bytes) -> char* {
    char* r = p;
    p += (bytes + 255) & ~(size_t)255;
    return r;
  };
  __bf16* wqbf = (__bf16*)take((size_t)768 * 768 * 2);
  __bf16* wkbf = (__bf16*)take((size_t)256 * 768 * 2);
  __bf16* wvbf = (__bf16*)take((size_t)256 * 768 * 2);
  __bf16* wobf = (__bf16*)take((size_t)768 * 768 * 2);
  __bf16* Qbf  = (__bf16*)take((size_t)MROWS * 768 * 2);
  __bf16* Kbf  = (__bf16*)take((size_t)MROWS * 256 * 2);
  __bf16* VTbf = (__bf16*)take((size_t)MROWS * 256 * 2);
  __bf16* Obf  = (__bf16*)take((size_t)MROWS * 768 * 2);
  size_t used = (size_t)(p - (char*)d_ws);

  const size_t XBF_B  = (size_t)MROWS * 768 * 2;
  const size_t QKV_B  = (size_t)MROWS * NQKV * 2;  // bf16
  const size_t TEMP_B = XBF_B + QKV_B;

  char* tp;
  if (used + TEMP_B + 1024 <= ws_size) {
    tp = p;
  } else {
    // tail of the attn output region; fully consumed before attn_kernel writes
    tp = (char*)(((uintptr_t)((char*)d_out + (size_t)out_size * 4 - TEMP_B)) & ~(uintptr_t)255);
  }
  __bf16* Xbf  = (__bf16*)tp;  tp += XBF_B;
  __bf16* QKVb = (__bf16*)tp;

  // ---- 1. fused casts (one launch) ----
  {
    const int total8 = MROWS * 768 / 8 + 2 * (768 * 768 / 8) + 2 * (256 * 768 / 8);
    cast_all<<<(total8 + 255) / 256, 256, 0, stream>>>(X, wq, wo, wk, wv,
                                                       Xbf, wqbf, wobf, wkbf, wvbf);
  }

  // ---- 2. fused QKV projection (bf16 output, 2-phase dbuf) ----
  gemm_qkv<<<dim3(MROWS / 128, NQKV / 128), 256, 0, stream>>>(Xbf, wqbf, wkbf, wvbf, QKVb);

  // ---- 3. vectorized RoPE (Q+K) + V transpose, both bf16 in ----
  {
    const int totalG = MROWS * NH_Q * 8 + MROWS * NKV_ * 8;  // 1048576
    rope_both<<<(totalG + 255) / 256, 256, 0, stream>>>(QKVb, fc, fs, Qbf, Kbf);
  }
  transpose_v<<<dim3(MROWS / 64, 4), 256, 0, stream>>>(QKVb, VTbf);

  // ---- 4. attention (8 waves/block; writes attn fp32 + Obf bf16) ----
  attn_kernel<<<dim3(48 * 64), 512, 0, stream>>>(Qbf, Kbf, VTbf, attn, Obf);

  // ---- 5. output projection ----
  gemm_xwT<<<dim3(MROWS / 128, 768 / 128), 256, 0, stream>>>(Obf, wobf, out0, MROWS, 768, 768);
}